// Round 6
// baseline (349.975 us; speedup 1.0000x reference)
//
#include <hip/hip_runtime.h>

#define BATCH 4096
#define ISZ   1024
#define HSZ   2048

typedef __bf16 bf16x8 __attribute__((ext_vector_type(8)));
typedef float  f32x4  __attribute__((ext_vector_type(4)));

// ---------- fp32 <-> bf16 ----------
__device__ __forceinline__ unsigned short f2bf(float f) {
  unsigned u = __builtin_bit_cast(unsigned, f);
  u += 0x7fffu + ((u >> 16) & 1u);
  return (unsigned short)(u >> 16);
}
__device__ __forceinline__ float bf2f(unsigned short s) {
  unsigned u = ((unsigned)s) << 16;
  return __builtin_bit_cast(float, u);
}

// ---------- cvt1: the 6 tensors gate_rz depends on ----------
struct CvtArgs {
  const float* src[6];
  unsigned short* dst[6];
  int cum[7];   // prefix sums of float4 counts
};

__global__ __launch_bounds__(256) void cvt_all_kernel(CvtArgs a, int total4) {
  int i = blockIdx.x * 256 + threadIdx.x;
  if (i >= total4) return;
  int s = 0;
#pragma unroll
  for (int k = 0; k < 5; ++k) s += (i >= a.cum[k + 1]) ? 1 : 0;
  int off = i - a.cum[s];
  float4 f = ((const float4*)a.src[s])[off];
  ushort4 o;
  o.x = f2bf(f.x); o.y = f2bf(f.y); o.z = f2bf(f.z); o.w = f2bf(f.w);
  ((ushort4*)a.dst[s])[off] = o;
}

// ---------- staging: BK=64, XOR-8 swizzled LDS (conflict-free, verified R2) ----------
// 128-row tile, 256-thread block: 1024 16-B chunks, 4/thread.
__device__ __forceinline__ void stage_tile64(const unsigned short* __restrict__ g, int ldK,
                                             int tileRow, int k0, char* lds, int t) {
  char* l0 = lds + ((t >> 6) << 10);  // wave-uniform base
#pragma unroll
  for (int k = 0; k < 4; ++k) {
    int linear = t + k * 256;        // chunk id, 0..1023
    int row = linear >> 3;           // 0..127
    int cs  = linear & 7;
    int c   = cs ^ (row & 7);        // XOR swizzle on global side
    const unsigned short* gp = g + (size_t)(tileRow + row) * ldK + (k0 + c * 8);
    __builtin_amdgcn_global_load_lds((const __attribute__((address_space(1))) void*)gp,
                                     (__attribute__((address_space(3))) void*)(l0 + k * 4096),
                                     16, 0, 0);
  }
}

// ---------- 128x128 GEMM segment, 4 waves (verified R3: 937 TF) ----------
// Accumulates A[rowBase..+128, k0..k0+K) * W[colBase..+128, k0..k0+K)^T
__device__ __forceinline__ void gemm_seg(const unsigned short* __restrict__ A,
                                         const unsigned short* __restrict__ W,
                                         int ldK, int kBeg, int kEnd,
                                         int rowBase, int colBase,
                                         char* ldsA, char* ldsB,
                                         f32x4 (&acc)[4][4], int t) {
  const int lane = t & 63;
  const int wid  = t >> 6;
  const int wm   = wid >> 1, wn = wid & 1;
  const int lrow = lane & 15;
  const int quad = lane >> 4;
  const int r7   = lrow & 7;
  for (int k0 = kBeg; k0 < kEnd; k0 += 64) {
    stage_tile64(A, ldK, rowBase, k0, ldsA, t);
    stage_tile64(W, ldK, colBase, k0, ldsB, t);
    __syncthreads();
#pragma unroll
    for (int kk = 0; kk < 2; ++kk) {
      const int swz = (((kk << 2) | quad) ^ r7) * 16;
      bf16x8 af[4], bfr[4];
#pragma unroll
      for (int i = 0; i < 4; ++i) {
        af[i]  = *(const bf16x8*)(ldsA + (wm * 64 + i * 16 + lrow) * 128 + swz);
        bfr[i] = *(const bf16x8*)(ldsB + (wn * 64 + i * 16 + lrow) * 128 + swz);
      }
#pragma unroll
      for (int i = 0; i < 4; ++i)
#pragma unroll
        for (int j = 0; j < 4; ++j)
          acc[i][j] = __builtin_amdgcn_mfma_f32_16x16x32_bf16(af[i], bfr[j], acc[i][j], 0, 0, 0);
    }
    __syncthreads();
  }
}

__device__ __forceinline__ float fast_sigmoid(float v) {
  return 1.0f / (1.0f + __expf(-v));
}
__device__ __forceinline__ float fast_tanh(float v) {
  float e = __expf(2.0f * v);
  return 1.0f - 2.0f / (e + 1.0f);   // safe at +/-inf
}

// ---------- Kernel A: z==0 plane converts Wh/Uh (overlapped); z==1,2 are R,Z ----------
__global__ __launch_bounds__(256, 4) void gate_rz(
    const unsigned short* __restrict__ xb, const unsigned short* __restrict__ hb,
    const unsigned short* __restrict__ Wr, const unsigned short* __restrict__ Ur,
    const unsigned short* __restrict__ Wz, const unsigned short* __restrict__ Uz,
    const float* __restrict__ br, const float* __restrict__ bz,
    const float* __restrict__ Wh32, const float* __restrict__ Uh32,
    unsigned short* __restrict__ Whb, unsigned short* __restrict__ Uhb,
    unsigned short* __restrict__ rh, unsigned short* __restrict__ Zbuf) {
  __shared__ char lds[32768];
  const int t = threadIdx.x;

  if (blockIdx.z == 0) {
    // dispatched first: converts Wh+Uh while gemm planes backfill the CUs
    const int NW = (HSZ * ISZ) / 4;
    const int NU = (HSZ * HSZ) / 4;
    int tid = (blockIdx.x + (blockIdx.y << 4)) * 256 + t;   // 0..131071
    for (int i = tid; i < NW + NU; i += 512 * 256) {
      const float4* s4 = (i < NW) ? (const float4*)Wh32 + i
                                  : (const float4*)Uh32 + (i - NW);
      ushort4* d4 = (i < NW) ? (ushort4*)Whb + i
                             : (ushort4*)Uhb + (i - NW);
      float4 f = *s4;
      ushort4 o;
      o.x = f2bf(f.x); o.y = f2bf(f.y); o.z = f2bf(f.z); o.w = f2bf(f.w);
      *d4 = o;
    }
    return;
  }

  char* ldsA = lds;
  char* ldsB = lds + 16384;
  int lin = blockIdx.x + (blockIdx.y << 4) + ((blockIdx.z - 1) << 9);
  int xcd = lin & 7, s = lin >> 3;
  int bx = xcd * 2 + (s & 1);
  int by = (s >> 1) & 31;
  int bz_ = s >> 6;

  const int rowBase = by * 128;
  const int colBase = bx * 128;
  const bool isZ = (bz_ != 0);
  const unsigned short* W = isZ ? Wz : Wr;
  const unsigned short* U = isZ ? Uz : Ur;
  const float* biasP = isZ ? bz : br;

  f32x4 acc[4][4];
#pragma unroll
  for (int i = 0; i < 4; ++i)
#pragma unroll
    for (int j = 0; j < 4; ++j)
      acc[i][j] = (f32x4){0.f, 0.f, 0.f, 0.f};

  gemm_seg(xb, W, ISZ, 0, ISZ, rowBase, colBase, ldsA, ldsB, acc, t);
  gemm_seg(hb, U, HSZ, 0, HSZ, rowBase, colBase, ldsA, ldsB, acc, t);

  const int lane = t & 63, wid = t >> 6;
  const int wm = wid >> 1, wn = wid & 1, lrow = lane & 15, quad = lane >> 4;
#pragma unroll
  for (int i = 0; i < 4; ++i) {
#pragma unroll
    for (int j = 0; j < 4; ++j) {
      int col = colBase + wn * 64 + j * 16 + lrow;
      float bv = biasP[col];
#pragma unroll
      for (int r = 0; r < 4; ++r) {
        int row = rowBase + wm * 64 + i * 16 + quad * 4 + r;
        float sg = fast_sigmoid(acc[i][j][r] + bv);
        int idx = row * HSZ + col;
        if (isZ) {
          Zbuf[idx] = f2bf(sg);
        } else {
          rh[idx] = f2bf(sg * bf2f(hb[idx]));
        }
      }
    }
  }
}

// ---------- Kernel B: split-K h-GEMM. 1024 blocks, 4-wave, 4 blocks/CU ----------
// z=0: x@Wh^T (K=1024) + rh@Uh^T K in [0,512)   -> P0
// z=1: rh@Uh^T K in [512,2048)                  -> P1
__global__ __launch_bounds__(256, 4) void gate_hk(
    const unsigned short* __restrict__ xb, const unsigned short* __restrict__ rhb,
    const unsigned short* __restrict__ Wh, const unsigned short* __restrict__ Uh,
    float* __restrict__ P0, float* __restrict__ P1) {
  __shared__ char lds[32768];
  char* ldsA = lds;
  char* ldsB = lds + 16384;
  const int t = threadIdx.x;

  int lin = blockIdx.x + (blockIdx.y << 4);   // 512 per z-plane
  int xcd = lin & 7, s = lin >> 3;
  int bx = xcd * 2 + (s & 1);
  int by = s >> 1;

  const int rowBase = by * 128;
  const int colBase = bx * 128;
  const int kz = blockIdx.z;

  f32x4 acc[4][4];
#pragma unroll
  for (int i = 0; i < 4; ++i)
#pragma unroll
    for (int j = 0; j < 4; ++j)
      acc[i][j] = (f32x4){0.f, 0.f, 0.f, 0.f};

  if (kz == 0) {
    gemm_seg(xb,  Wh, ISZ, 0, ISZ,    rowBase, colBase, ldsA, ldsB, acc, t);
    gemm_seg(rhb, Uh, HSZ, 0, 512,    rowBase, colBase, ldsA, ldsB, acc, t);
  } else {
    gemm_seg(rhb, Uh, HSZ, 512, HSZ,  rowBase, colBase, ldsA, ldsB, acc, t);
  }

  float* P = (kz == 0) ? P0 : P1;
  const int lane = t & 63, wid = t >> 6;
  const int wm = wid >> 1, wn = wid & 1, lrow = lane & 15, quad = lane >> 4;
#pragma unroll
  for (int i = 0; i < 4; ++i) {
#pragma unroll
    for (int j = 0; j < 4; ++j) {
      int col = colBase + wn * 64 + j * 16 + lrow;
#pragma unroll
      for (int r = 0; r < 4; ++r) {
        int row = rowBase + wm * 64 + i * 16 + quad * 4 + r;
        P[row * HSZ + col] = acc[i][j][r];
      }
    }
  }
}

// ---------- Kernel C: blend epilogue (memory-bound) ----------
__global__ __launch_bounds__(256) void blend_kernel(
    const float* __restrict__ P0, const float* __restrict__ P1,
    const float* __restrict__ bh, const unsigned short* __restrict__ Zbuf,
    const float* __restrict__ hprev, float* __restrict__ out, int n4) {
  int i = blockIdx.x * 256 + threadIdx.x;
  if (i >= n4) return;
  float4 p0 = ((const float4*)P0)[i];
  float4 p1 = ((const float4*)P1)[i];
  float4 bv = *(const float4*)(bh + ((i * 4) & (HSZ - 1)));
  ushort4 zb = ((const ushort4*)Zbuf)[i];
  float4 h  = ((const float4*)hprev)[i];
  float4 o;
  {
    float hp = fast_tanh(p0.x + p1.x + bv.x); float z = bf2f(zb.x);
    o.x = h.x + z * (hp - h.x);
  }
  {
    float hp = fast_tanh(p0.y + p1.y + bv.y); float z = bf2f(zb.y);
    o.y = h.y + z * (hp - h.y);
  }
  {
    float hp = fast_tanh(p0.z + p1.z + bv.z); float z = bf2f(zb.z);
    o.z = h.z + z * (hp - h.z);
  }
  {
    float hp = fast_tanh(p0.w + p1.w + bv.w); float z = bf2f(zb.w);
    o.w = h.w + z * (hp - h.w);
  }
  ((float4*)out)[i] = o;
}

// ---------- host ----------
extern "C" void kernel_launch(void* const* d_in, const int* in_sizes, int n_in,
                              void* d_out, int out_size, void* d_ws, size_t ws_size,
                              hipStream_t stream) {
  (void)in_sizes; (void)n_in; (void)out_size; (void)ws_size;
  const float* x     = (const float*)d_in[0];
  const float* hprev = (const float*)d_in[1];
  const float* Wh    = (const float*)d_in[2];
  const float* Wz    = (const float*)d_in[3];
  const float* Wr    = (const float*)d_in[4];
  const float* Uh    = (const float*)d_in[5];
  const float* Uz    = (const float*)d_in[6];
  const float* Ur    = (const float*)d_in[7];
  const float* bh    = (const float*)d_in[8];
  const float* bz    = (const float*)d_in[9];
  const float* br    = (const float*)d_in[10];
  float* out = (float*)d_out;

  char* ws = (char*)d_ws;
  size_t off = 0;
  auto alloc = [&](size_t bytes) { char* p = ws + off; off += bytes; return p; };
  unsigned short* xb  = (unsigned short*)alloc((size_t)BATCH * ISZ * 2);
  unsigned short* hb  = (unsigned short*)alloc((size_t)BATCH * HSZ * 2);
  unsigned short* Wrb = (unsigned short*)alloc((size_t)HSZ * ISZ * 2);
  unsigned short* Wzb = (unsigned short*)alloc((size_t)HSZ * ISZ * 2);
  unsigned short* Whb = (unsigned short*)alloc((size_t)HSZ * ISZ * 2);
  unsigned short* Urb = (unsigned short*)alloc((size_t)HSZ * HSZ * 2);
  unsigned short* Uzb = (unsigned short*)alloc((size_t)HSZ * HSZ * 2);
  unsigned short* Uhb = (unsigned short*)alloc((size_t)HSZ * HSZ * 2);
  unsigned short* rhb = (unsigned short*)alloc((size_t)BATCH * HSZ * 2);
  unsigned short* Zb  = (unsigned short*)alloc((size_t)BATCH * HSZ * 2);
  float*          P0  = (float*)alloc((size_t)BATCH * HSZ * 4);
  float*          P1  = (float*)alloc((size_t)BATCH * HSZ * 4);

  // cvt1: only what gate_rz needs (Wh/Uh converted inside gate_rz's z==0 plane)
  CvtArgs ca;
  const float* srcs[6]      = {x, hprev, Wr, Wz, Ur, Uz};
  unsigned short* dsts[6]   = {xb, hb, Wrb, Wzb, Urb, Uzb};
  int n4s[6] = {BATCH * ISZ / 4, BATCH * HSZ / 4,
                HSZ * ISZ / 4, HSZ * ISZ / 4,
                HSZ * HSZ / 4, HSZ * HSZ / 4};
  int cum = 0;
  for (int i = 0; i < 6; ++i) {
    ca.src[i] = srcs[i];
    ca.dst[i] = dsts[i];
    ca.cum[i] = cum;
    cum += n4s[i];
  }
  ca.cum[6] = cum;
  cvt_all_kernel<<<(cum + 255) / 256, 256, 0, stream>>>(ca, cum);

  dim3 gridA(HSZ / 128, BATCH / 128, 3);   // z=0: Wh/Uh cvt plane; z=1,2: R,Z gemm
  gate_rz<<<gridA, 256, 0, stream>>>(xb, hb, Wrb, Urb, Wzb, Uzb, br, bz,
                                     Wh, Uh, Whb, Uhb, rhb, Zb);

  dim3 gridB(HSZ / 128, BATCH / 128, 2);   // split-K: 1024 blocks @ 4/CU
  gate_hk<<<gridB, 256, 0, stream>>>(xb, rhb, Whb, Uhb, P0, P1);

  int n4 = BATCH * HSZ / 4;
  blend_kernel<<<(n4 + 255) / 256, 256, 0, stream>>>(P0, P1, bh, Zb, hprev, out, n4);
}